// Round 8
// baseline (206.295 us; speedup 1.0000x reference)
//
#include <hip/hip_runtime.h>
#include <cstdint>
#include <cstddef>

#define ALPHA 0.01f
#define A1    0.99f
#define B_    8
#define S_    2048
#define H_    2048
#define NCH   8      // chunks along S
#define CL    256    // chunk length
#define NKT   64     // K tiles in GEMM (2048/32)

typedef __attribute__((ext_vector_type(8))) short bf16x8;
typedef __attribute__((ext_vector_type(4))) float f32x4;

__device__ __forceinline__ unsigned short f2bf(float f) {
    unsigned int u = __float_as_uint(f);
    u += 0x7FFFu + ((u >> 16) & 1u);   // round-to-nearest-even
    return (unsigned short)(u >> 16);
}

__device__ __forceinline__ void gld16(const void* g, void* l) {
    __builtin_amdgcn_global_load_lds(
        (const __attribute__((address_space(1))) unsigned int*)g,
        (__attribute__((address_space(3))) unsigned int*)l, 16, 0, 0);
}

// ---------------- W cast: f32 -> bf16 ----------------
__global__ void ema_cast_w(const float* __restrict__ W, short* __restrict__ Wb) {
    int i = (blockIdx.x * 256 + threadIdx.x) * 4;
    float4 v = *(const float4*)(W + i);
    short4 o;
    o.x = (short)f2bf(v.x);
    o.y = (short)f2bf(v.y);
    o.z = (short)f2bf(v.z);
    o.w = (short)f2bf(v.w);
    *(short4*)(Wb + i) = o;
}

// ---------------- pass 1: chunk-local EMA carries (float2, 2 chains/thread) ----
__global__ __launch_bounds__(256) void ema_carry_kernel(
        const float* __restrict__ x, float* __restrict__ carry) {
    int bid = blockIdx.x;                 // 256 blocks: b(8) x c(8) x hg(4)
    int hg = bid & 3;
    int c  = (bid >> 2) & 7;
    int b  = bid >> 5;
    int h0 = (hg << 9) + (threadIdx.x << 1);
    const float2* px = (const float2*)(x + ((size_t)(b * S_) + (size_t)c * CL) * H_ + h0);
    const int STR = H_ / 2;               // float2 stride per sequence step
    float s0, s1;
    int i0;
    if (c == 0) { float2 v = px[0]; s0 = v.x; s1 = v.y; i0 = 1; }
    else        { s0 = 0.f; s1 = 0.f;                   i0 = 0; }
    #pragma unroll 8
    for (int i = i0; i < CL; ++i) {
        float2 v = px[(size_t)i * STR];
        s0 = fmaf(A1, s0, ALPHA * v.x);
        s1 = fmaf(A1, s1, ALPHA * v.y);
    }
    *(float2*)(carry + ((b << 3) + c) * H_ + h0) = (float2){s0, s1};
}

// ---------------- pass 2: apply carry-in, rescan, write packed bf16 s ----------
__global__ __launch_bounds__(256) void ema_apply_kernel(
        const float* __restrict__ x, const float* __restrict__ carry,
        unsigned short* __restrict__ sb) {
    int bid = blockIdx.x;                 // 256 blocks: b(8) x c(8) x hg(4)
    int hg = bid & 3;
    int c  = (bid >> 2) & 7;
    int b  = bid >> 5;
    int h0 = (hg << 9) + (threadIdx.x << 1);

    float A256 = A1;                      // 0.99^256 via 8 squarings
    #pragma unroll
    for (int q = 0; q < 8; ++q) A256 *= A256;

    float c0 = 0.f, c1 = 0.f, f = 1.f;
    for (int j = c - 1; j >= 0; --j) {
        float2 cv = *(const float2*)(carry + ((b << 3) + j) * H_ + h0);
        c0 = fmaf(cv.x, f, c0);
        c1 = fmaf(cv.y, f, c1);
        f *= A256;
    }

    size_t base = ((size_t)(b * S_) + (size_t)c * CL) * H_ + h0;
    const float2* px = (const float2*)(x + base);
    unsigned int*  pu = (unsigned int*)(sb + base);
    const int STR = H_ / 2;
    float s0, s1;
    int i0;
    if (c == 0) {
        float2 v = px[0]; s0 = v.x; s1 = v.y;
        pu[0] = (unsigned int)f2bf(s0) | ((unsigned int)f2bf(s1) << 16);
        i0 = 1;
    } else { s0 = c0; s1 = c1; i0 = 0; }
    #pragma unroll 8
    for (int i = i0; i < CL; ++i) {
        float2 v = px[(size_t)i * STR];
        s0 = fmaf(A1, s0, ALPHA * v.x);
        s1 = fmaf(A1, s1, ALPHA * v.y);
        pu[(size_t)i * STR] = (unsigned int)f2bf(s0) | ((unsigned int)f2bf(s1) << 16);
    }
}

// ---------------- GEMM: 128x256 tile, BK=32, 8 waves, 2 blocks/CU -------------
// out[m,n] = sum_k s[m,k]*W[n,k] + bias[n].  M=16384 N=2048 K=2048.
// 64x64 per wave (acc[4][4]); LDS 48 KiB double-buffered; launch_bounds(512,4)
// caps VGPR at 128 so TWO blocks co-schedule per CU: block A's barrier/LDS
// bursts overlap block B's MFMA bursts (m97/m114 mechanism).
// 64B LDS rows; swizzle s(row)=((row>>1)&3)<<4 applied on global source (write)
// and ds_read offset (read) -> every 8-lane b128 group tiles all 32 banks.
// Schedule per K-tile: reads -> BAR -> lgkm0 -> stage(t+2 into cur) -> 16 MFMA
// -> VMW(3) -> BAR.  Tile t's loads forced landed at end of tile t-1.

#define BAR __builtin_amdgcn_s_barrier()
#define WAIT_LGKM do { asm volatile("s_waitcnt lgkmcnt(0)" ::: "memory"); \
                       __builtin_amdgcn_sched_barrier(0); } while (0)
#define VMW(n) asm volatile("s_waitcnt vmcnt(" #n ")" ::: "memory")

#define STGA(kt, buf)    gld16(gA  + (size_t)(kt) * 64, &ldsA[buf][w << 9])
#define STGB(j, kt, buf) gld16(((j) ? gB1 : gB0) + (size_t)(kt) * 64, \
                               &ldsB[buf][((j) << 12) + (w << 9)])

#define LDAB do {                                                                  \
    const char* aB_ = (const char*)&ldsA[cur][0] + (wm << 12) + laneRow + cb;      \
    const char* bB_ = (const char*)&ldsB[cur][0] + (wn << 12) + laneRow + cb;      \
    _Pragma("unroll") for (int q_ = 0; q_ < 4; ++q_) {                             \
        Af[q_] = *(const bf16x8*)(aB_ + (q_ << 10));                               \
        Bf[q_] = *(const bf16x8*)(bB_ + (q_ << 10)); } } while (0)

#define MM do { __builtin_amdgcn_s_setprio(1);                                     \
    _Pragma("unroll") for (int mi_ = 0; mi_ < 4; ++mi_)                            \
    _Pragma("unroll") for (int n_ = 0; n_ < 4; ++n_)                               \
        acc[mi_][n_] = __builtin_amdgcn_mfma_f32_16x16x32_bf16(                    \
            Af[mi_], Bf[n_], acc[mi_][n_], 0, 0, 0);                               \
    __builtin_amdgcn_s_setprio(0); } while (0)

__global__ __launch_bounds__(512, 4) void ema_gemm_kernel(
        const short* __restrict__ Sb, const short* __restrict__ Wb,
        const float* __restrict__ bias, float* __restrict__ out) {
    __shared__ short ldsA[2][4096];    // 128x32 bf16 per buffer (8 KiB x2)
    __shared__ short ldsB[2][8192];    // 256x32 bf16 per buffer (16 KiB x2)

    int bid = blockIdx.x;              // 1024 blocks = 2 per CU, one pass
    int swz = ((bid & 7) << 7) | (bid >> 3);   // XCD swizzle, bijective (1024 % 8 == 0)
    int tm = swz >> 3;                 // 0..127
    int tn = swz & 7;                  // 0..7

    int tid  = threadIdx.x;
    int lane = tid & 63;
    int w    = tid >> 6;               // 0..7
    int wm   = w >> 2;                 // 0..1  (64-row half)
    int wn   = w & 3;                  // 0..3  (64-col quarter)

    const int K2 = H_ * 2;             // row stride in bytes (4096)
    int rowA = tm << 7;
    int rowB = tn << 8;

    // ---- staging source pointers (pre-swizzled global addresses) ----
    // staged row = 16w + (lane>>2); s(row) = ((row>>1)&3)<<4 = ((lane>>3)&3)<<4
    int strow = (w << 4) + (lane >> 2);
    int colb  = (((lane & 3) ^ ((lane >> 3) & 3)) << 4);
    const char* gA  = (const char*)Sb + (size_t)(rowA + strow) * K2 + colb;
    const char* gB0 = (const char*)Wb + (size_t)(rowB + strow) * K2 + colb;
    const char* gB1 = (const char*)Wb + (size_t)(rowB + 128 + strow) * K2 + colb;

    // ---- fragment ds_read offsets: row=(lane&15)+16*frag; s(row)=((lane>>1)&3)<<4
    int laneRow = (lane & 15) << 6;
    int cb = ((lane >> 4) ^ ((lane >> 1) & 3)) << 4;

    f32x4 acc[4][4];
    #pragma unroll
    for (int i = 0; i < 4; ++i)
        #pragma unroll
        for (int j = 0; j < 4; ++j)
            acc[i][j] = (f32x4){0.f, 0.f, 0.f, 0.f};
    bf16x8 Af[4], Bf[4];

    int colg = (tn << 8) + (wn << 6) + (lane & 15);
    float bb[4];
    #pragma unroll
    for (int n = 0; n < 4; ++n) bb[n] = bias[colg + (n << 4)];

    // ---- prologue: stage tiles 0 and 1 (3 loads each); force tile 0 ----
    STGA(0, 0); STGB(0, 0, 0); STGB(1, 0, 0);
    STGA(1, 1); STGB(0, 1, 1); STGB(1, 1, 1);
    VMW(3);
    BAR;

    for (int t = 0; t < NKT; ++t) {
        int cur = t & 1;
        LDAB;                              // 8 ds_read_b128 of tile t
        BAR;
        WAIT_LGKM;
        if (t < NKT - 2) {                 // stage t+2 into cur's (now dead) buffer
            STGA(t + 2, cur); STGB(0, t + 2, cur); STGB(1, t + 2, cur);
        }
        MM;                                // 16 MFMA
        if (t < NKT - 2)       { VMW(3); } // forces tile t+1's 3 loads
        else if (t == NKT - 2) { VMW(0); } // drain for the last tile
        BAR;
    }

    // ---- epilogue: C/D layout col=lane&15, row=(lane>>4)*4+q ----
    int rowg = (tm << 7) + (wm << 6) + ((lane >> 4) << 2);
    #pragma unroll
    for (int mi = 0; mi < 4; ++mi) {
        #pragma unroll
        for (int n = 0; n < 4; ++n) {
            int c = colg + (n << 4);
            size_t rb = (size_t)(rowg + (mi << 4)) << 11;
            #pragma unroll
            for (int q = 0; q < 4; ++q)
                out[rb + ((size_t)q << 11) + c] = acc[mi][n][q] + bb[n];
        }
    }
}

extern "C" void kernel_launch(void* const* d_in, const int* in_sizes, int n_in,
                              void* d_out, int out_size, void* d_ws, size_t ws_size,
                              hipStream_t stream) {
    const float* x    = (const float*)d_in[0];   // [B,S,H] f32
    const float* W    = (const float*)d_in[1];   // [H,H] f32
    const float* bias = (const float*)d_in[2];   // [H] f32
    float* out = (float*)d_out;                  // [B,S,H] f32

    char* ws = (char*)d_ws;
    size_t s_bytes = (size_t)B_ * S_ * H_ * 2;   // 67.1 MB bf16 s
    size_t w_bytes = (size_t)H_ * H_ * 2;        // 8.4 MB bf16 W
    unsigned short* s_bf  = (unsigned short*)ws;
    short*          w_bf  = (short*)(ws + s_bytes);
    float*          carry = (float*)(ws + s_bytes + w_bytes);  // 8*8*2048 f32

    ema_cast_w<<<(H_ * H_) / 1024, 256, 0, stream>>>(W, w_bf);
    ema_carry_kernel<<<B_ * NCH * (H_ / 512), 256, 0, stream>>>(x, carry);
    ema_apply_kernel<<<B_ * NCH * (H_ / 512), 256, 0, stream>>>(x, carry, s_bf);
    ema_gemm_kernel<<<(16384 / 128) * (2048 / 256), 512, 0, stream>>>(
        (const short*)s_bf, w_bf, bias, out);
}

// Round 9
// 204.915 us; speedup vs baseline: 1.0067x; 1.0067x over previous
//
#include <hip/hip_runtime.h>
#include <cstdint>
#include <cstddef>

#define ALPHA 0.01f
#define A1    0.99f
#define B_    8
#define S_    2048
#define H_    2048
#define NCH   8      // chunks along S
#define CL    256    // chunk length
#define NKT   32     // K tiles in GEMM (2048/64)

typedef __attribute__((ext_vector_type(8))) short bf16x8;
typedef __attribute__((ext_vector_type(4))) float f32x4;

__device__ __forceinline__ unsigned short f2bf(float f) {
    unsigned int u = __float_as_uint(f);
    u += 0x7FFFu + ((u >> 16) & 1u);   // round-to-nearest-even
    return (unsigned short)(u >> 16);
}

__device__ __forceinline__ void gld16(const void* g, void* l) {
    __builtin_amdgcn_global_load_lds(
        (const __attribute__((address_space(1))) unsigned int*)g,
        (__attribute__((address_space(3))) unsigned int*)l, 16, 0, 0);
}

// ---------------- W cast: f32 -> bf16 ----------------
__global__ void ema_cast_w(const float* __restrict__ W, short* __restrict__ Wb) {
    int i = (blockIdx.x * 256 + threadIdx.x) * 4;
    float4 v = *(const float4*)(W + i);
    short4 o;
    o.x = (short)f2bf(v.x);
    o.y = (short)f2bf(v.y);
    o.z = (short)f2bf(v.z);
    o.w = (short)f2bf(v.w);
    *(short4*)(Wb + i) = o;
}

// ---------------- pass 1: chunk-local EMA carries (float2, 2 chains/thread) ----
__global__ __launch_bounds__(256) void ema_carry_kernel(
        const float* __restrict__ x, float* __restrict__ carry) {
    int bid = blockIdx.x;                 // 256 blocks: b(8) x c(8) x hg(4)
    int hg = bid & 3;
    int c  = (bid >> 2) & 7;
    int b  = bid >> 5;
    int h0 = (hg << 9) + (threadIdx.x << 1);
    const float2* px = (const float2*)(x + ((size_t)(b * S_) + (size_t)c * CL) * H_ + h0);
    const int STR = H_ / 2;               // float2 stride per sequence step
    float s0, s1;
    int i0;
    if (c == 0) { float2 v = px[0]; s0 = v.x; s1 = v.y; i0 = 1; }
    else        { s0 = 0.f; s1 = 0.f;                   i0 = 0; }
    #pragma unroll 8
    for (int i = i0; i < CL; ++i) {
        float2 v = px[(size_t)i * STR];
        s0 = fmaf(A1, s0, ALPHA * v.x);
        s1 = fmaf(A1, s1, ALPHA * v.y);
    }
    *(float2*)(carry + ((b << 3) + c) * H_ + h0) = (float2){s0, s1};
}

// ---------------- pass 2: apply carry-in, rescan, write packed bf16 s ----------
__global__ __launch_bounds__(256) void ema_apply_kernel(
        const float* __restrict__ x, const float* __restrict__ carry,
        unsigned short* __restrict__ sb) {
    int bid = blockIdx.x;                 // 256 blocks: b(8) x c(8) x hg(4)
    int hg = bid & 3;
    int c  = (bid >> 2) & 7;
    int b  = bid >> 5;
    int h0 = (hg << 9) + (threadIdx.x << 1);

    float A256 = A1;                      // 0.99^256 via 8 squarings
    #pragma unroll
    for (int q = 0; q < 8; ++q) A256 *= A256;

    float c0 = 0.f, c1 = 0.f, f = 1.f;
    for (int j = c - 1; j >= 0; --j) {
        float2 cv = *(const float2*)(carry + ((b << 3) + j) * H_ + h0);
        c0 = fmaf(cv.x, f, c0);
        c1 = fmaf(cv.y, f, c1);
        f *= A256;
    }

    size_t base = ((size_t)(b * S_) + (size_t)c * CL) * H_ + h0;
    const float2* px = (const float2*)(x + base);
    unsigned int*  pu = (unsigned int*)(sb + base);
    const int STR = H_ / 2;
    float s0, s1;
    int i0;
    if (c == 0) {
        float2 v = px[0]; s0 = v.x; s1 = v.y;
        pu[0] = (unsigned int)f2bf(s0) | ((unsigned int)f2bf(s1) << 16);
        i0 = 1;
    } else { s0 = c0; s1 = c1; i0 = 0; }
    #pragma unroll 8
    for (int i = i0; i < CL; ++i) {
        float2 v = px[(size_t)i * STR];
        s0 = fmaf(A1, s0, ALPHA * v.x);
        s1 = fmaf(A1, s1, ALPHA * v.y);
        pu[(size_t)i * STR] = (unsigned int)f2bf(s0) | ((unsigned int)f2bf(s1) << 16);
    }
}

// ---------------- GEMM: 256x256 tile, BK=64, 8 waves, read/MFMA overlap -------
// out[m,n] = sum_k s[m,k]*W[n,k] + bias[n].  M=16384 N=2048 K=2048.
// Round-5 geometry/swizzle/epilogue; NEW schedule: all 24 ds_reads of tile t
// issued up front as C loads (compiler emits counted lgkmcnt per MFMA operand),
// so LDA1/LDB1 drain UNDER MM(0,*). Ledger per tile: reads; MM(0,*); lgkm0;
// BAR; stage all 8 of t+2 into cur (dead); MM(1,*); VMW(8) [forces t+1]; BAR.
// Swizzle: byte ^= ((storage_row & 7) << 4); both-sides. Conflict-free (r5).

#define BAR __builtin_amdgcn_s_barrier()
#define WAIT_LGKM do { asm volatile("s_waitcnt lgkmcnt(0)" ::: "memory"); \
                       __builtin_amdgcn_sched_barrier(0); } while (0)
#define VMW(n) asm volatile("s_waitcnt vmcnt(" #n ")" ::: "memory")

#define STGA(i, kt, buf) gld16(gA[i] + (size_t)(kt) * 128, &ldsA[buf][((i) << 12) + (w << 9)])
#define STGB(i, kt, buf) gld16(gB[i] + (size_t)(kt) * 128, &ldsB[buf][((i) << 12) + (w << 9)])

#define LDAm(dst, mh) do { int ra_ = (wm << 1) | (mh);                             \
    const char* base_ = (const char*)&ldsA[cur][0]                                 \
        + (((((ra_ & 1) << 1) | (ra_ >> 1))) << 13) + laneRow;                     \
    _Pragma("unroll") for (int m_ = 0; m_ < 4; ++m_) {                             \
        dst[m_][0] = *(const bf16x8*)(base_ + (m_ << 11) + ck0);                   \
        dst[m_][1] = *(const bf16x8*)(base_ + (m_ << 11) + ck1); } } while (0)

#define LDB(nh) do { const char* base_ = (const char*)&ldsB[cur][0]                \
        + ((nh) << 14) + (wn << 12) + laneRow;                                     \
    _Pragma("unroll") for (int n_ = 0; n_ < 2; ++n_) {                             \
        Bf[(nh) * 2 + n_][0] = *(const bf16x8*)(base_ + (n_ << 11) + ck0);         \
        Bf[(nh) * 2 + n_][1] = *(const bf16x8*)(base_ + (n_ << 11) + ck1); } } while (0)

#define MMq(Asrc, mh, nh) do { __builtin_amdgcn_s_setprio(1);                      \
    _Pragma("unroll") for (int m_ = 0; m_ < 4; ++m_)                               \
    _Pragma("unroll") for (int n_ = 0; n_ < 2; ++n_)                               \
    _Pragma("unroll") for (int k_ = 0; k_ < 2; ++k_)                               \
        acc[(mh) * 4 + m_][(nh) * 2 + n_] = __builtin_amdgcn_mfma_f32_16x16x32_bf16( \
            Asrc[m_][k_], Bf[(nh) * 2 + n_][k_], acc[(mh) * 4 + m_][(nh) * 2 + n_], 0, 0, 0); \
    __builtin_amdgcn_s_setprio(0); } while (0)

__global__ __launch_bounds__(512, 2) void ema_gemm_kernel(
        const short* __restrict__ Sb, const short* __restrict__ Wb,
        const float* __restrict__ bias, float* __restrict__ out) {
    __shared__ short ldsA[2][16384];   // 64 KiB
    __shared__ short ldsB[2][16384];   // 64 KiB

    int bid = blockIdx.x;
    int swz = ((bid & 7) << 6) | (bid >> 3);   // XCD swizzle, bijective (512 % 8 == 0)
    int tm = swz >> 3;                 // 0..63
    int tn = swz & 7;                  // 0..7

    int tid  = threadIdx.x;
    int lane = tid & 63;
    int w    = tid >> 6;               // 0..7
    int wm   = w >> 2;                 // 0..1
    int wn   = w & 3;                  // 0..3

    const int K2 = H_ * 2;             // row stride in bytes (4096)
    int rowA = tm << 8;
    int rowB = tn << 8;

    // ---- staging source pointers (per-lane, pre-swizzled global addresses) ----
    int rowoff = (w << 3) + (lane >> 3);                 // 0..63 within an 8KB issue
    int colb   = (((lane & 7) ^ (lane >> 3)) << 4);      // inverse-swizzled k-byte
    const char* SbB = (const char*)Sb;
    const char* WbB = (const char*)Wb;
    const char* gA[4];
    const char* gB[4];
    #pragma unroll
    for (int i = 0; i < 4; ++i) {
        int lq = ((i & 1) << 1) | (i >> 1);              // storage slot -> logical A quarter
        gA[i] = SbB + (size_t)(rowA + lq * 64 + rowoff) * K2 + colb;
        int pos = 2 * i + (w >> 2);                      // B storage 32-row slot
        int ls  = ((pos & 3) << 1) | (pos >> 2);         // -> logical slice
        gB[i] = WbB + (size_t)(rowB + ls * 32 + ((w & 3) << 3) + (lane >> 3)) * K2 + colb;
    }

    // ---- fragment ds_read offsets (round-5 conflict-free swizzle) ----
    int laneRow = (lane & 15) << 7;
    int ck0 = (((lane >> 4)) ^ (lane & 7)) << 4;
    int ck1 = ((4 + (lane >> 4)) ^ (lane & 7)) << 4;

    f32x4 acc[8][4];
    #pragma unroll
    for (int i = 0; i < 8; ++i)
        #pragma unroll
        for (int j = 0; j < 4; ++j)
            acc[i][j] = (f32x4){0.f, 0.f, 0.f, 0.f};
    bf16x8 Af0[4][2], Af1[4][2], Bf[4][2];

    int colg = (tn << 8) + (wn << 6) + (lane & 15);
    float bb[4];
    #pragma unroll
    for (int n = 0; n < 4; ++n) bb[n] = bias[colg + (n << 4)];

    // ---- prologue: stage tiles 0 and 1 fully (16 loads); force tile 0 ----
    STGA(0, 0, 0); STGA(1, 0, 0); STGA(2, 0, 0); STGA(3, 0, 0);
    STGB(0, 0, 0); STGB(1, 0, 0); STGB(2, 0, 0); STGB(3, 0, 0);
    STGA(0, 1, 1); STGA(1, 1, 1); STGA(2, 1, 1); STGA(3, 1, 1);
    STGB(0, 1, 1); STGB(1, 1, 1); STGB(2, 1, 1); STGB(3, 1, 1);
    VMW(8);
    BAR;

    for (int t = 0; t < NKT; ++t) {
        int cur = t & 1;
        // all 24 ds_reads of tile t issued up front; compiler inserts counted
        // lgkm waits so LDB(1)/LDA1 drain under MM(0,*)
        LDAm(Af0, 0); LDB(0); LDB(1); LDAm(Af1, 1);
        MMq(Af0, 0, 0);
        MMq(Af0, 0, 1);
        WAIT_LGKM;                         // all reads of cur done (incl. Af1)
        BAR;                               // -> cur is dead for staging
        if (t < NKT - 2) {                 // stage tile t+2 into cur (8 loads)
            STGA(0, t + 2, cur); STGA(1, t + 2, cur);
            STGA(2, t + 2, cur); STGA(3, t + 2, cur);
            STGB(0, t + 2, cur); STGB(1, t + 2, cur);
            STGB(2, t + 2, cur); STGB(3, t + 2, cur);
        }
        MMq(Af1, 1, 0);
        MMq(Af1, 1, 1);
        if (t < NKT - 2)       { VMW(8); } // forces tile t+1's 8-load batch
        else if (t == NKT - 2) { VMW(0); } // drain for the last tile
        BAR;
    }

    // ---- epilogue: C/D layout col=lane&15, row=(lane>>4)*4+q ----
    int rowg = (tm << 8) + (wm << 7) + ((lane >> 4) << 2);
    #pragma unroll
    for (int m = 0; m < 8; ++m) {
        #pragma unroll
        for (int n = 0; n < 4; ++n) {
            int c = colg + (n << 4);
            size_t rb = (size_t)(rowg + (m << 4)) << 11;
            #pragma unroll
            for (int q = 0; q < 4; ++q)
                out[rb + ((size_t)q << 11) + c] = acc[m][n][q] + bb[n];
        }
    }
}

extern "C" void kernel_launch(void* const* d_in, const int* in_sizes, int n_in,
                              void* d_out, int out_size, void* d_ws, size_t ws_size,
                              hipStream_t stream) {
    const float* x    = (const float*)d_in[0];   // [B,S,H] f32
    const float* W    = (const float*)d_in[1];   // [H,H] f32
    const float* bias = (const float*)d_in[2];   // [H] f32
    float* out = (float*)d_out;                  // [B,S,H] f32

    char* ws = (char*)d_ws;
    size_t s_bytes = (size_t)B_ * S_ * H_ * 2;   // 67.1 MB bf16 s
    size_t w_bytes = (size_t)H_ * H_ * 2;        // 8.4 MB bf16 W
    unsigned short* s_bf  = (unsigned short*)ws;
    short*          w_bf  = (short*)(ws + s_bytes);
    float*          carry = (float*)(ws + s_bytes + w_bytes);  // 8*8*2048 f32

    ema_cast_w<<<(H_ * H_) / 1024, 256, 0, stream>>>(W, w_bf);
    ema_carry_kernel<<<B_ * NCH * (H_ / 512), 256, 0, stream>>>(x, carry);
    ema_apply_kernel<<<B_ * NCH * (H_ / 512), 256, 0, stream>>>(x, carry, s_bf);
    ema_gemm_kernel<<<(16384 / 256) * (2048 / 256), 512, 0, stream>>>(
        (const short*)s_bf, w_bf, bias, out);
}

// Round 10
// 192.612 us; speedup vs baseline: 1.0710x; 1.0639x over previous
//
#include <hip/hip_runtime.h>
#include <cstdint>
#include <cstddef>

#define ALPHA 0.01f
#define A1    0.99f
#define B_    8
#define S_    2048
#define H_    2048
#define NCH   8      // chunks along S
#define CL    256    // chunk length
#define NKT   32     // K tiles in GEMM (2048/64)

typedef __attribute__((ext_vector_type(8))) short bf16x8;
typedef __attribute__((ext_vector_type(4))) float f32x4;

__device__ __forceinline__ unsigned short f2bf(float f) {
    unsigned int u = __float_as_uint(f);
    u += 0x7FFFu + ((u >> 16) & 1u);   // round-to-nearest-even
    return (unsigned short)(u >> 16);
}

__device__ __forceinline__ void gld16(const void* g, void* l) {
    __builtin_amdgcn_global_load_lds(
        (const __attribute__((address_space(1))) unsigned int*)g,
        (__attribute__((address_space(3))) unsigned int*)l, 16, 0, 0);
}

// ---------------- W cast: f32 -> bf16 ----------------
__global__ void ema_cast_w(const float* __restrict__ W, short* __restrict__ Wb) {
    int i = (blockIdx.x * 256 + threadIdx.x) * 4;
    float4 v = *(const float4*)(W + i);
    short4 o;
    o.x = (short)f2bf(v.x);
    o.y = (short)f2bf(v.y);
    o.z = (short)f2bf(v.z);
    o.w = (short)f2bf(v.w);
    *(short4*)(Wb + i) = o;
}

// ---------------- pass 1: chunk-local EMA carries (float2, 2 chains/thread) ----
__global__ __launch_bounds__(256) void ema_carry_kernel(
        const float* __restrict__ x, float* __restrict__ carry) {
    int bid = blockIdx.x;                 // 256 blocks: b(8) x c(8) x hg(4)
    int hg = bid & 3;
    int c  = (bid >> 2) & 7;
    int b  = bid >> 5;
    int h0 = (hg << 9) + (threadIdx.x << 1);
    const float2* px = (const float2*)(x + ((size_t)(b * S_) + (size_t)c * CL) * H_ + h0);
    const int STR = H_ / 2;               // float2 stride per sequence step
    float s0, s1;
    int i0;
    if (c == 0) { float2 v = px[0]; s0 = v.x; s1 = v.y; i0 = 1; }
    else        { s0 = 0.f; s1 = 0.f;                   i0 = 0; }
    #pragma unroll 8
    for (int i = i0; i < CL; ++i) {
        float2 v = px[(size_t)i * STR];
        s0 = fmaf(A1, s0, ALPHA * v.x);
        s1 = fmaf(A1, s1, ALPHA * v.y);
    }
    *(float2*)(carry + ((b << 3) + c) * H_ + h0) = (float2){s0, s1};
}

// ---------------- pass 2: apply carry-in, rescan, write packed bf16 s ----------
__global__ __launch_bounds__(256) void ema_apply_kernel(
        const float* __restrict__ x, const float* __restrict__ carry,
        unsigned short* __restrict__ sb) {
    int bid = blockIdx.x;                 // 256 blocks: b(8) x c(8) x hg(4)
    int hg = bid & 3;
    int c  = (bid >> 2) & 7;
    int b  = bid >> 5;
    int h0 = (hg << 9) + (threadIdx.x << 1);

    float A256 = A1;                      // 0.99^256 via 8 squarings
    #pragma unroll
    for (int q = 0; q < 8; ++q) A256 *= A256;

    float c0 = 0.f, c1 = 0.f, f = 1.f;
    for (int j = c - 1; j >= 0; --j) {
        float2 cv = *(const float2*)(carry + ((b << 3) + j) * H_ + h0);
        c0 = fmaf(cv.x, f, c0);
        c1 = fmaf(cv.y, f, c1);
        f *= A256;
    }

    size_t base = ((size_t)(b * S_) + (size_t)c * CL) * H_ + h0;
    const float2* px = (const float2*)(x + base);
    unsigned int*  pu = (unsigned int*)(sb + base);
    const int STR = H_ / 2;
    float s0, s1;
    int i0;
    if (c == 0) {
        float2 v = px[0]; s0 = v.x; s1 = v.y;
        pu[0] = (unsigned int)f2bf(s0) | ((unsigned int)f2bf(s1) << 16);
        i0 = 1;
    } else { s0 = c0; s1 = c1; i0 = 0; }
    #pragma unroll 8
    for (int i = i0; i < CL; ++i) {
        float2 v = px[(size_t)i * STR];
        s0 = fmaf(A1, s0, ALPHA * v.x);
        s1 = fmaf(A1, s1, ALPHA * v.y);
        pu[(size_t)i * STR] = (unsigned int)f2bf(s0) | ((unsigned int)f2bf(s1) << 16);
    }
}

// ---------------- GEMM: 256x256 tile, BK=64, 8 waves, round-2 cadence ---------
// out[m,n] = sum_k s[m,k]*W[n,k] + bias[n].  M=16384 N=2048 K=2048.
// CHAMPION CONFIG (round 5; A/B-proven best of 6 schedule variants):
// 16x16x32 MFMA, dual per-tile VMW(6), 3-bit XOR swizzle (conflict-free),
// half-tile staging: ph0 A2nd(t+1), ph1 B2nd(t+1), ph2 A1st(t+2), ph3 B1st(t+2).
// Swizzle: byte ^= ((storage_row & 7) << 4); both-sides (pre-swizzled global
// source for linear global_load_lds + swizzled ds_read address).

#define BAR __builtin_amdgcn_s_barrier()
#define WAIT_LGKM do { asm volatile("s_waitcnt lgkmcnt(0)" ::: "memory"); \
                       __builtin_amdgcn_sched_barrier(0); } while (0)
#define VMW(n) asm volatile("s_waitcnt vmcnt(" #n ")" ::: "memory")

#define STGA(i, kt, buf) gld16(gA[i] + (size_t)(kt) * 128, &ldsA[buf][((i) << 12) + (w << 9)])
#define STGB(i, kt, buf) gld16(gB[i] + (size_t)(kt) * 128, &ldsB[buf][((i) << 12) + (w << 9)])

#define LDA(mh) do { int ra_ = (wm << 1) | (mh);                                   \
    const char* base_ = (const char*)&ldsA[cur][0]                                 \
        + (((((ra_ & 1) << 1) | (ra_ >> 1))) << 13) + laneRow;                     \
    _Pragma("unroll") for (int m_ = 0; m_ < 4; ++m_) {                             \
        Af[m_][0] = *(const bf16x8*)(base_ + (m_ << 11) + ck0);                    \
        Af[m_][1] = *(const bf16x8*)(base_ + (m_ << 11) + ck1); } } while (0)

#define LDB(nh) do { const char* base_ = (const char*)&ldsB[cur][0]                \
        + ((nh) << 14) + (wn << 12) + laneRow;                                     \
    _Pragma("unroll") for (int n_ = 0; n_ < 2; ++n_) {                             \
        Bf[(nh) * 2 + n_][0] = *(const bf16x8*)(base_ + (n_ << 11) + ck0);         \
        Bf[(nh) * 2 + n_][1] = *(const bf16x8*)(base_ + (n_ << 11) + ck1); } } while (0)

#define MM(mh, nh) do { __builtin_amdgcn_s_setprio(1);                             \
    _Pragma("unroll") for (int m_ = 0; m_ < 4; ++m_)                               \
    _Pragma("unroll") for (int n_ = 0; n_ < 2; ++n_)                               \
    _Pragma("unroll") for (int k_ = 0; k_ < 2; ++k_)                               \
        acc[(mh) * 4 + m_][(nh) * 2 + n_] = __builtin_amdgcn_mfma_f32_16x16x32_bf16( \
            Af[m_][k_], Bf[(nh) * 2 + n_][k_], acc[(mh) * 4 + m_][(nh) * 2 + n_], 0, 0, 0); \
    __builtin_amdgcn_s_setprio(0); } while (0)

__global__ __launch_bounds__(512, 2) void ema_gemm_kernel(
        const short* __restrict__ Sb, const short* __restrict__ Wb,
        const float* __restrict__ bias, float* __restrict__ out) {
    __shared__ short ldsA[2][16384];   // 64 KiB
    __shared__ short ldsB[2][16384];   // 64 KiB

    int bid = blockIdx.x;
    int swz = ((bid & 7) << 6) | (bid >> 3);   // XCD swizzle, bijective (512 % 8 == 0)
    int tm = swz >> 3;                 // 0..63
    int tn = swz & 7;                  // 0..7

    int tid  = threadIdx.x;
    int lane = tid & 63;
    int w    = tid >> 6;               // 0..7
    int wm   = w >> 2;                 // 0..1
    int wn   = w & 3;                  // 0..3

    const int K2 = H_ * 2;             // row stride in bytes (4096)
    int rowA = tm << 8;
    int rowB = tn << 8;

    // ---- staging source pointers (per-lane, pre-swizzled global addresses) ----
    int rowoff = (w << 3) + (lane >> 3);                 // 0..63 within an 8KB issue
    int colb   = (((lane & 7) ^ (lane >> 3)) << 4);      // inverse-swizzled k-byte
    const char* SbB = (const char*)Sb;
    const char* WbB = (const char*)Wb;
    const char* gA[4];
    const char* gB[4];
    #pragma unroll
    for (int i = 0; i < 4; ++i) {
        int lq = ((i & 1) << 1) | (i >> 1);              // storage slot -> logical A quarter
        gA[i] = SbB + (size_t)(rowA + lq * 64 + rowoff) * K2 + colb;
        int pos = 2 * i + (w >> 2);                      // B storage 32-row slot
        int ls  = ((pos & 3) << 1) | (pos >> 2);         // -> logical slice
        gB[i] = WbB + (size_t)(rowB + ls * 32 + ((w & 3) << 3) + (lane >> 3)) * K2 + colb;
    }

    // ---- fragment ds_read offsets (swizzled) ----
    int laneRow = (lane & 15) << 7;
    int ck0 = (((lane >> 4)) ^ (lane & 7)) << 4;
    int ck1 = ((4 + (lane >> 4)) ^ (lane & 7)) << 4;

    f32x4 acc[8][4];
    #pragma unroll
    for (int i = 0; i < 8; ++i)
        #pragma unroll
        for (int j = 0; j < 4; ++j)
            acc[i][j] = (f32x4){0.f, 0.f, 0.f, 0.f};
    bf16x8 Af[4][2], Bf[4][2];

    int colg = (tn << 8) + (wn << 6) + (lane & 15);
    float bb[4];
    #pragma unroll
    for (int n = 0; n < 4; ++n) bb[n] = bias[colg + (n << 4)];

    // ---- prologue: tile0 full + tile1 first halves; leave 6 loads in flight ----
    STGA(0, 0, 0); STGA(1, 0, 0); STGB(0, 0, 0); STGB(1, 0, 0);   // A1st(0), B1st(0)
    STGA(2, 0, 0); STGA(3, 0, 0); STGB(2, 0, 0); STGB(3, 0, 0);   // A2nd(0), B2nd(0)
    STGA(0, 1, 1); STGA(1, 1, 1); STGB(0, 1, 1); STGB(1, 1, 1);   // A1st(1), B1st(1)
    VMW(6);
    BAR;

    for (int t = 0; t < NKT; ++t) {
        int cur = t & 1, nxt = cur ^ 1;
        bool i01 = (t < NKT - 1), i23 = (t < NKT - 2);
        // phase 0: compute (mh0,nh0); stage A2nd(t+1)
        LDA(0); LDB(0);
        if (i01) { STGA(2, t + 1, nxt); STGA(3, t + 1, nxt); }
        BAR; WAIT_LGKM;
        MM(0, 0);
        if (i01) { VMW(6); }
        BAR;
        // phase 1: compute (mh0,nh1); stage B2nd(t+1)
        LDB(1);
        if (i01) { STGB(2, t + 1, nxt); STGB(3, t + 1, nxt); }
        BAR; WAIT_LGKM;
        MM(0, 1);
        BAR;
        // phase 2: compute (mh1,nh0); stage A1st(t+2) into dead quarters of cur
        LDA(1);
        if (i23) { STGA(0, t + 2, cur); STGA(1, t + 2, cur); }
        BAR; WAIT_LGKM;
        MM(1, 0);
        BAR;
        // phase 3: compute (mh1,nh1); stage B1st(t+2) into dead slices of cur
        if (i23) { STGB(0, t + 2, cur); STGB(1, t + 2, cur); }
        BAR;
        MM(1, 1);
        if (t == NKT - 2) { VMW(0); }          // entering last tile: drain
        else if (t < NKT - 2) { VMW(6); }      // steady state: 3 half-tiles in flight
        BAR;
    }

    // ---- epilogue: C/D layout col=lane&15, row=(lane>>4)*4+q ----
    int rowg = (tm << 8) + (wm << 7) + ((lane >> 4) << 2);
    #pragma unroll
    for (int m = 0; m < 8; ++m) {
        #pragma unroll
        for (int n = 0; n < 4; ++n) {
            int c = colg + (n << 4);
            size_t rb = (size_t)(rowg + (m << 4)) << 11;
            #pragma unroll
            for (int q = 0; q < 4; ++q)
                out[rb + ((size_t)q << 11) + c] = acc[m][n][q] + bb[n];
        }
    }
}

extern "C" void kernel_launch(void* const* d_in, const int* in_sizes, int n_in,
                              void* d_out, int out_size, void* d_ws, size_t ws_size,
                              hipStream_t stream) {
    const float* x    = (const float*)d_in[0];   // [B,S,H] f32
    const float* W    = (const float*)d_in[1];   // [H,H] f32
    const float* bias = (const float*)d_in[2];   // [H] f32
    float* out = (float*)d_out;                  // [B,S,H] f32

    char* ws = (char*)d_ws;
    size_t s_bytes = (size_t)B_ * S_ * H_ * 2;   // 67.1 MB bf16 s
    size_t w_bytes = (size_t)H_ * H_ * 2;        // 8.4 MB bf16 W
    unsigned short* s_bf  = (unsigned short*)ws;
    short*          w_bf  = (short*)(ws + s_bytes);
    float*          carry = (float*)(ws + s_bytes + w_bytes);  // 8*8*2048 f32

    ema_cast_w<<<(H_ * H_) / 1024, 256, 0, stream>>>(W, w_bf);
    ema_carry_kernel<<<B_ * NCH * (H_ / 512), 256, 0, stream>>>(x, carry);
    ema_apply_kernel<<<B_ * NCH * (H_ / 512), 256, 0, stream>>>(x, carry, s_bf);
    ema_gemm_kernel<<<(16384 / 256) * (2048 / 256), 512, 0, stream>>>(
        (const short*)s_bf, w_bf, bias, out);
}

// Round 11
// 190.968 us; speedup vs baseline: 1.0803x; 1.0086x over previous
//
#include <hip/hip_runtime.h>
#include <cstdint>
#include <cstddef>

#define ALPHA 0.01f
#define A1    0.99f
#define B_    8
#define S_    2048
#define H_    2048
#define NCH   8      // chunks along S
#define CL    256    // chunk length
#define NKT   32     // K tiles in GEMM (2048/64)

typedef __attribute__((ext_vector_type(8))) short bf16x8;
typedef __attribute__((ext_vector_type(4))) float f32x4;

__device__ __forceinline__ unsigned short f2bf(float f) {
    unsigned int u = __float_as_uint(f);
    u += 0x7FFFu + ((u >> 16) & 1u);   // round-to-nearest-even
    return (unsigned short)(u >> 16);
}

__device__ __forceinline__ void gld16(const void* g, void* l) {
    __builtin_amdgcn_global_load_lds(
        (const __attribute__((address_space(1))) unsigned int*)g,
        (__attribute__((address_space(3))) unsigned int*)l, 16, 0, 0);
}

// ---------------- W cast: f32 -> bf16 ----------------
__global__ void ema_cast_w(const float* __restrict__ W, short* __restrict__ Wb) {
    int i = (blockIdx.x * 256 + threadIdx.x) * 4;
    float4 v = *(const float4*)(W + i);
    short4 o;
    o.x = (short)f2bf(v.x);
    o.y = (short)f2bf(v.y);
    o.z = (short)f2bf(v.z);
    o.w = (short)f2bf(v.w);
    *(short4*)(Wb + i) = o;
}

// ---------------- pass 1: chunk-local EMA carries (float2, 2 chains/thread) ----
__global__ __launch_bounds__(256) void ema_carry_kernel(
        const float* __restrict__ x, float* __restrict__ carry) {
    int bid = blockIdx.x;                 // 256 blocks: b(8) x c(8) x hg(4)
    int hg = bid & 3;
    int c  = (bid >> 2) & 7;
    int b  = bid >> 5;
    int h0 = (hg << 9) + (threadIdx.x << 1);
    const float2* px = (const float2*)(x + ((size_t)(b * S_) + (size_t)c * CL) * H_ + h0);
    const int STR = H_ / 2;               // float2 stride per sequence step
    float s0, s1;
    int i0;
    if (c == 0) { float2 v = px[0]; s0 = v.x; s1 = v.y; i0 = 1; }
    else        { s0 = 0.f; s1 = 0.f;                   i0 = 0; }
    #pragma unroll 8
    for (int i = i0; i < CL; ++i) {
        float2 v = px[(size_t)i * STR];
        s0 = fmaf(A1, s0, ALPHA * v.x);
        s1 = fmaf(A1, s1, ALPHA * v.y);
    }
    *(float2*)(carry + ((b << 3) + c) * H_ + h0) = (float2){s0, s1};
}

// ---------------- pass 2: apply carry-in, rescan, write packed bf16 s ----------
__global__ __launch_bounds__(256) void ema_apply_kernel(
        const float* __restrict__ x, const float* __restrict__ carry,
        unsigned short* __restrict__ sb) {
    int bid = blockIdx.x;                 // 256 blocks: b(8) x c(8) x hg(4)
    int hg = bid & 3;
    int c  = (bid >> 2) & 7;
    int b  = bid >> 5;
    int h0 = (hg << 9) + (threadIdx.x << 1);

    float A256 = A1;                      // 0.99^256 via 8 squarings
    #pragma unroll
    for (int q = 0; q < 8; ++q) A256 *= A256;

    float c0 = 0.f, c1 = 0.f, f = 1.f;
    for (int j = c - 1; j >= 0; --j) {
        float2 cv = *(const float2*)(carry + ((b << 3) + j) * H_ + h0);
        c0 = fmaf(cv.x, f, c0);
        c1 = fmaf(cv.y, f, c1);
        f *= A256;
    }

    size_t base = ((size_t)(b * S_) + (size_t)c * CL) * H_ + h0;
    const float2* px = (const float2*)(x + base);
    unsigned int*  pu = (unsigned int*)(sb + base);
    const int STR = H_ / 2;
    float s0, s1;
    int i0;
    if (c == 0) {
        float2 v = px[0]; s0 = v.x; s1 = v.y;
        pu[0] = (unsigned int)f2bf(s0) | ((unsigned int)f2bf(s1) << 16);
        i0 = 1;
    } else { s0 = c0; s1 = c1; i0 = 0; }
    #pragma unroll 8
    for (int i = i0; i < CL; ++i) {
        float2 v = px[(size_t)i * STR];
        s0 = fmaf(A1, s0, ALPHA * v.x);
        s1 = fmaf(A1, s1, ALPHA * v.y);
        pu[(size_t)i * STR] = (unsigned int)f2bf(s0) | ((unsigned int)f2bf(s1) << 16);
    }
}

// ---------------- GEMM: 256x256 tile, BK=64, 8 waves, round-2 cadence ---------
// out[m,n] = sum_k s[m,k]*W[n,k] + bias[n].  M=16384 N=2048 K=2048.
// Champion (round 5/10) with ONE change: the explicit lgkmcnt(0)+sched_barrier
// drain before each MFMA cluster is REMOVED. LDS reads are plain C loads, so
// the compiler inserts counted lgkmcnt per MFMA operand (m97 asm evidence) --
// early MFMAs issue while later ds_reads are still in flight (read/MFMA
// overlap the explicit full drain was defeating).
// Ledger safety: staging writes land >=2 barriers after the region's last
// read phase, and each phase's MM consumes ALL its reads, so compiler waits
// drain every wave's reads before its next barrier.
// Swizzle: byte ^= ((storage_row & 7) << 4); both-sides. Conflict-free (r5).

#define BAR __builtin_amdgcn_s_barrier()
#define VMW(n) asm volatile("s_waitcnt vmcnt(" #n ")" ::: "memory")

#define STGA(i, kt, buf) gld16(gA[i] + (size_t)(kt) * 128, &ldsA[buf][((i) << 12) + (w << 9)])
#define STGB(i, kt, buf) gld16(gB[i] + (size_t)(kt) * 128, &ldsB[buf][((i) << 12) + (w << 9)])

#define LDA(mh) do { int ra_ = (wm << 1) | (mh);                                   \
    const char* base_ = (const char*)&ldsA[cur][0]                                 \
        + (((((ra_ & 1) << 1) | (ra_ >> 1))) << 13) + laneRow;                     \
    _Pragma("unroll") for (int m_ = 0; m_ < 4; ++m_) {                             \
        Af[m_][0] = *(const bf16x8*)(base_ + (m_ << 11) + ck0);                    \
        Af[m_][1] = *(const bf16x8*)(base_ + (m_ << 11) + ck1); } } while (0)

#define LDB(nh) do { const char* base_ = (const char*)&ldsB[cur][0]                \
        + ((nh) << 14) + (wn << 12) + laneRow;                                     \
    _Pragma("unroll") for (int n_ = 0; n_ < 2; ++n_) {                             \
        Bf[(nh) * 2 + n_][0] = *(const bf16x8*)(base_ + (n_ << 11) + ck0);         \
        Bf[(nh) * 2 + n_][1] = *(const bf16x8*)(base_ + (n_ << 11) + ck1); } } while (0)

#define MM(mh, nh) do { __builtin_amdgcn_s_setprio(1);                             \
    _Pragma("unroll") for (int m_ = 0; m_ < 4; ++m_)                               \
    _Pragma("unroll") for (int n_ = 0; n_ < 2; ++n_)                               \
    _Pragma("unroll") for (int k_ = 0; k_ < 2; ++k_)                               \
        acc[(mh) * 4 + m_][(nh) * 2 + n_] = __builtin_amdgcn_mfma_f32_16x16x32_bf16( \
            Af[m_][k_], Bf[(nh) * 2 + n_][k_], acc[(mh) * 4 + m_][(nh) * 2 + n_], 0, 0, 0); \
    __builtin_amdgcn_s_setprio(0); } while (0)

__global__ __launch_bounds__(512, 2) void ema_gemm_kernel(
        const short* __restrict__ Sb, const short* __restrict__ Wb,
        const float* __restrict__ bias, float* __restrict__ out) {
    __shared__ short ldsA[2][16384];   // 64 KiB
    __shared__ short ldsB[2][16384];   // 64 KiB

    int bid = blockIdx.x;
    int swz = ((bid & 7) << 6) | (bid >> 3);   // XCD swizzle, bijective (512 % 8 == 0)
    int tm = swz >> 3;                 // 0..63
    int tn = swz & 7;                  // 0..7

    int tid  = threadIdx.x;
    int lane = tid & 63;
    int w    = tid >> 6;               // 0..7
    int wm   = w >> 2;                 // 0..1
    int wn   = w & 3;                  // 0..3

    const int K2 = H_ * 2;             // row stride in bytes (4096)
    int rowA = tm << 8;
    int rowB = tn << 8;

    // ---- staging source pointers (per-lane, pre-swizzled global addresses) ----
    int rowoff = (w << 3) + (lane >> 3);                 // 0..63 within an 8KB issue
    int colb   = (((lane & 7) ^ (lane >> 3)) << 4);      // inverse-swizzled k-byte
    const char* SbB = (const char*)Sb;
    const char* WbB = (const char*)Wb;
    const char* gA[4];
    const char* gB[4];
    #pragma unroll
    for (int i = 0; i < 4; ++i) {
        int lq = ((i & 1) << 1) | (i >> 1);              // storage slot -> logical A quarter
        gA[i] = SbB + (size_t)(rowA + lq * 64 + rowoff) * K2 + colb;
        int pos = 2 * i + (w >> 2);                      // B storage 32-row slot
        int ls  = ((pos & 3) << 1) | (pos >> 2);         // -> logical slice
        gB[i] = WbB + (size_t)(rowB + ls * 32 + ((w & 3) << 3) + (lane >> 3)) * K2 + colb;
    }

    // ---- fragment ds_read offsets (swizzled) ----
    int laneRow = (lane & 15) << 7;
    int ck0 = (((lane >> 4)) ^ (lane & 7)) << 4;
    int ck1 = ((4 + (lane >> 4)) ^ (lane & 7)) << 4;

    f32x4 acc[8][4];
    #pragma unroll
    for (int i = 0; i < 8; ++i)
        #pragma unroll
        for (int j = 0; j < 4; ++j)
            acc[i][j] = (f32x4){0.f, 0.f, 0.f, 0.f};
    bf16x8 Af[4][2], Bf[4][2];

    int colg = (tn << 8) + (wn << 6) + (lane & 15);
    float bb[4];
    #pragma unroll
    for (int n = 0; n < 4; ++n) bb[n] = bias[colg + (n << 4)];

    // ---- prologue: tile0 full + tile1 first halves; leave 6 loads in flight ----
    STGA(0, 0, 0); STGA(1, 0, 0); STGB(0, 0, 0); STGB(1, 0, 0);   // A1st(0), B1st(0)
    STGA(2, 0, 0); STGA(3, 0, 0); STGB(2, 0, 0); STGB(3, 0, 0);   // A2nd(0), B2nd(0)
    STGA(0, 1, 1); STGA(1, 1, 1); STGB(0, 1, 1); STGB(1, 1, 1);   // A1st(1), B1st(1)
    VMW(6);
    BAR;

    for (int t = 0; t < NKT; ++t) {
        int cur = t & 1, nxt = cur ^ 1;
        bool i01 = (t < NKT - 1), i23 = (t < NKT - 2);
        // phase 0: compute (mh0,nh0); stage A2nd(t+1)
        LDA(0); LDB(0);
        if (i01) { STGA(2, t + 1, nxt); STGA(3, t + 1, nxt); }
        BAR;
        MM(0, 0);                          // compiler-counted lgkm waits overlap reads
        if (i01) { VMW(6); }
        BAR;
        // phase 1: compute (mh0,nh1); stage B2nd(t+1)
        LDB(1);
        if (i01) { STGB(2, t + 1, nxt); STGB(3, t + 1, nxt); }
        BAR;
        MM(0, 1);
        BAR;
        // phase 2: compute (mh1,nh0); stage A1st(t+2) into dead quarters of cur
        LDA(1);
        if (i23) { STGA(0, t + 2, cur); STGA(1, t + 2, cur); }
        BAR;
        MM(1, 0);
        BAR;
        // phase 3: compute (mh1,nh1); stage B1st(t+2) into dead slices of cur
        if (i23) { STGB(0, t + 2, cur); STGB(1, t + 2, cur); }
        BAR;
        MM(1, 1);
        if (t == NKT - 2) { VMW(0); }          // entering last tile: drain
        else if (t < NKT - 2) { VMW(6); }      // steady state: 3 half-tiles in flight
        BAR;
    }

    // ---- epilogue: C/D layout col=lane&15, row=(lane>>4)*4+q ----
    int rowg = (tm << 8) + (wm << 7) + ((lane >> 4) << 2);
    #pragma unroll
    for (int m = 0; m < 8; ++m) {
        #pragma unroll
        for (int n = 0; n < 4; ++n) {
            int c = colg + (n << 4);
            size_t rb = (size_t)(rowg + (m << 4)) << 11;
            #pragma unroll
            for (int q = 0; q < 4; ++q)
                out[rb + ((size_t)q << 11) + c] = acc[m][n][q] + bb[n];
        }
    }
}

extern "C" void kernel_launch(void* const* d_in, const int* in_sizes, int n_in,
                              void* d_out, int out_size, void* d_ws, size_t ws_size,
                              hipStream_t stream) {
    const float* x    = (const float*)d_in[0];   // [B,S,H] f32
    const float* W    = (const float*)d_in[1];   // [H,H] f32
    const float* bias = (const float*)d_in[2];   // [H] f32
    float* out = (float*)d_out;                  // [B,S,H] f32

    char* ws = (char*)d_ws;
    size_t s_bytes = (size_t)B_ * S_ * H_ * 2;   // 67.1 MB bf16 s
    size_t w_bytes = (size_t)H_ * H_ * 2;        // 8.4 MB bf16 W
    unsigned short* s_bf  = (unsigned short*)ws;
    short*          w_bf  = (short*)(ws + s_bytes);
    float*          carry = (float*)(ws + s_bytes + w_bytes);  // 8*8*2048 f32

    ema_cast_w<<<(H_ * H_) / 1024, 256, 0, stream>>>(W, w_bf);
    ema_carry_kernel<<<B_ * NCH * (H_ / 512), 256, 0, stream>>>(x, carry);
    ema_apply_kernel<<<B_ * NCH * (H_ / 512), 256, 0, stream>>>(x, carry, s_bf);
    ema_gemm_kernel<<<(16384 / 256) * (2048 / 256), 512, 0, stream>>>(
        (const short*)s_bf, w_bf, bias, out);
}

// Round 12
// 186.257 us; speedup vs baseline: 1.1076x; 1.0253x over previous
//
#include <hip/hip_runtime.h>
#include <cstdint>
#include <cstddef>

#define ALPHA 0.01f
#define A1    0.99f
#define B_    8
#define S_    2048
#define H_    2048
#define NCH   8      // chunks along S
#define CL    256    // chunk length
#define NKT   32     // K tiles in GEMM (2048/64)

typedef __attribute__((ext_vector_type(8))) short bf16x8;
typedef __attribute__((ext_vector_type(4))) float f32x4;

__device__ __forceinline__ unsigned short f2bf(float f) {
    unsigned int u = __float_as_uint(f);
    u += 0x7FFFu + ((u >> 16) & 1u);   // round-to-nearest-even
    return (unsigned short)(u >> 16);
}

__device__ __forceinline__ void gld16(const void* g, void* l) {
    __builtin_amdgcn_global_load_lds(
        (const __attribute__((address_space(1))) unsigned int*)g,
        (__attribute__((address_space(3))) unsigned int*)l, 16, 0, 0);
}

// ---------------- W cast: f32 -> bf16 ----------------
__global__ void ema_cast_w(const float* __restrict__ W, short* __restrict__ Wb) {
    int i = (blockIdx.x * 256 + threadIdx.x) * 4;
    float4 v = *(const float4*)(W + i);
    short4 o;
    o.x = (short)f2bf(v.x);
    o.y = (short)f2bf(v.y);
    o.z = (short)f2bf(v.z);
    o.w = (short)f2bf(v.w);
    *(short4*)(Wb + i) = o;
}

// ---------------- pass 1: chunk-local EMA carries (float2, 2 chains/thread) ----
__global__ __launch_bounds__(256) void ema_carry_kernel(
        const float* __restrict__ x, float* __restrict__ carry) {
    int bid = blockIdx.x;                 // 256 blocks: b(8) x c(8) x hg(4)
    int hg = bid & 3;
    int c  = (bid >> 2) & 7;
    int b  = bid >> 5;
    int h0 = (hg << 9) + (threadIdx.x << 1);
    const float2* px = (const float2*)(x + ((size_t)(b * S_) + (size_t)c * CL) * H_ + h0);
    const int STR = H_ / 2;               // float2 stride per sequence step
    float s0, s1;
    int i0;
    if (c == 0) { float2 v = px[0]; s0 = v.x; s1 = v.y; i0 = 1; }
    else        { s0 = 0.f; s1 = 0.f;                   i0 = 0; }
    #pragma unroll 8
    for (int i = i0; i < CL; ++i) {
        float2 v = px[(size_t)i * STR];
        s0 = fmaf(A1, s0, ALPHA * v.x);
        s1 = fmaf(A1, s1, ALPHA * v.y);
    }
    *(float2*)(carry + ((b << 3) + c) * H_ + h0) = (float2){s0, s1};
}

// ---------------- pass 2: apply carry-in, rescan, write packed bf16 s ----------
__global__ __launch_bounds__(256) void ema_apply_kernel(
        const float* __restrict__ x, const float* __restrict__ carry,
        unsigned short* __restrict__ sb) {
    int bid = blockIdx.x;                 // 256 blocks: b(8) x c(8) x hg(4)
    int hg = bid & 3;
    int c  = (bid >> 2) & 7;
    int b  = bid >> 5;
    int h0 = (hg << 9) + (threadIdx.x << 1);

    float A256 = A1;                      // 0.99^256 via 8 squarings
    #pragma unroll
    for (int q = 0; q < 8; ++q) A256 *= A256;

    float c0 = 0.f, c1 = 0.f, f = 1.f;
    for (int j = c - 1; j >= 0; --j) {
        float2 cv = *(const float2*)(carry + ((b << 3) + j) * H_ + h0);
        c0 = fmaf(cv.x, f, c0);
        c1 = fmaf(cv.y, f, c1);
        f *= A256;
    }

    size_t base = ((size_t)(b * S_) + (size_t)c * CL) * H_ + h0;
    const float2* px = (const float2*)(x + base);
    unsigned int*  pu = (unsigned int*)(sb + base);
    const int STR = H_ / 2;
    float s0, s1;
    int i0;
    if (c == 0) {
        float2 v = px[0]; s0 = v.x; s1 = v.y;
        pu[0] = (unsigned int)f2bf(s0) | ((unsigned int)f2bf(s1) << 16);
        i0 = 1;
    } else { s0 = c0; s1 = c1; i0 = 0; }
    #pragma unroll 8
    for (int i = i0; i < CL; ++i) {
        float2 v = px[(size_t)i * STR];
        s0 = fmaf(A1, s0, ALPHA * v.x);
        s1 = fmaf(A1, s1, ALPHA * v.y);
        pu[(size_t)i * STR] = (unsigned int)f2bf(s0) | ((unsigned int)f2bf(s1) << 16);
    }
}

// ---------------- GEMM: 256x256 tile, BK=64, 8 waves ---------------------------
// out[m,n] = sum_k s[m,k]*W[n,k] + bias[n].  M=16384 N=2048 K=2048.
// Champion cadence with the post-MM barriers REMOVED (8 -> 4 BAR/tile): each
// phase = {reads; stage; [VMW]; BAR; MM}. Next phase's ds_reads issue while
// this phase's MFMAs execute (cross-phase overlap the extra BAR was blocking).
// VMW moved BEFORE the phase BAR so write-visibility chain (VMW -> BAR -> read)
// holds; FIFO forced-sets identical to champion. A-fragments split Af0/Af1 to
// kill the register WAR between LDA(ph2) and MM(0,1).
// Swizzle: byte ^= ((storage_row & 7) << 4); both-sides. Conflict-free (r5).

#define BAR __builtin_amdgcn_s_barrier()
#define VMW(n) asm volatile("s_waitcnt vmcnt(" #n ")" ::: "memory")

#define STGA(i, kt, buf) gld16(gA[i] + (size_t)(kt) * 128, &ldsA[buf][((i) << 12) + (w << 9)])
#define STGB(i, kt, buf) gld16(gB[i] + (size_t)(kt) * 128, &ldsB[buf][((i) << 12) + (w << 9)])

#define LDA(dst, mh) do { int ra_ = (wm << 1) | (mh);                              \
    const char* base_ = (const char*)&ldsA[cur][0]                                 \
        + (((((ra_ & 1) << 1) | (ra_ >> 1))) << 13) + laneRow;                     \
    _Pragma("unroll") for (int m_ = 0; m_ < 4; ++m_) {                             \
        dst[m_][0] = *(const bf16x8*)(base_ + (m_ << 11) + ck0);                   \
        dst[m_][1] = *(const bf16x8*)(base_ + (m_ << 11) + ck1); } } while (0)

#define LDB(nh) do { const char* base_ = (const char*)&ldsB[cur][0]                \
        + ((nh) << 14) + (wn << 12) + laneRow;                                     \
    _Pragma("unroll") for (int n_ = 0; n_ < 2; ++n_) {                             \
        Bf[(nh) * 2 + n_][0] = *(const bf16x8*)(base_ + (n_ << 11) + ck0);         \
        Bf[(nh) * 2 + n_][1] = *(const bf16x8*)(base_ + (n_ << 11) + ck1); } } while (0)

#define MM(Asrc, mh, nh) do { __builtin_amdgcn_s_setprio(1);                       \
    _Pragma("unroll") for (int m_ = 0; m_ < 4; ++m_)                               \
    _Pragma("unroll") for (int n_ = 0; n_ < 2; ++n_)                               \
    _Pragma("unroll") for (int k_ = 0; k_ < 2; ++k_)                               \
        acc[(mh) * 4 + m_][(nh) * 2 + n_] = __builtin_amdgcn_mfma_f32_16x16x32_bf16( \
            Asrc[m_][k_], Bf[(nh) * 2 + n_][k_], acc[(mh) * 4 + m_][(nh) * 2 + n_], 0, 0, 0); \
    __builtin_amdgcn_s_setprio(0); } while (0)

__global__ __launch_bounds__(512, 2) void ema_gemm_kernel(
        const short* __restrict__ Sb, const short* __restrict__ Wb,
        const float* __restrict__ bias, float* __restrict__ out) {
    __shared__ short ldsA[2][16384];   // 64 KiB
    __shared__ short ldsB[2][16384];   // 64 KiB

    int bid = blockIdx.x;
    int swz = ((bid & 7) << 6) | (bid >> 3);   // XCD swizzle, bijective (512 % 8 == 0)
    int tm = swz >> 3;                 // 0..63
    int tn = swz & 7;                  // 0..7

    int tid  = threadIdx.x;
    int lane = tid & 63;
    int w    = tid >> 6;               // 0..7
    int wm   = w >> 2;                 // 0..1
    int wn   = w & 3;                  // 0..3

    const int K2 = H_ * 2;             // row stride in bytes (4096)
    int rowA = tm << 8;
    int rowB = tn << 8;

    // ---- staging source pointers (per-lane, pre-swizzled global addresses) ----
    int rowoff = (w << 3) + (lane >> 3);                 // 0..63 within an 8KB issue
    int colb   = (((lane & 7) ^ (lane >> 3)) << 4);      // inverse-swizzled k-byte
    const char* SbB = (const char*)Sb;
    const char* WbB = (const char*)Wb;
    const char* gA[4];
    const char* gB[4];
    #pragma unroll
    for (int i = 0; i < 4; ++i) {
        int lq = ((i & 1) << 1) | (i >> 1);              // storage slot -> logical A quarter
        gA[i] = SbB + (size_t)(rowA + lq * 64 + rowoff) * K2 + colb;
        int pos = 2 * i + (w >> 2);                      // B storage 32-row slot
        int ls  = ((pos & 3) << 1) | (pos >> 2);         // -> logical slice
        gB[i] = WbB + (size_t)(rowB + ls * 32 + ((w & 3) << 3) + (lane >> 3)) * K2 + colb;
    }

    // ---- fragment ds_read offsets (swizzled) ----
    int laneRow = (lane & 15) << 7;
    int ck0 = (((lane >> 4)) ^ (lane & 7)) << 4;
    int ck1 = ((4 + (lane >> 4)) ^ (lane & 7)) << 4;

    f32x4 acc[8][4];
    #pragma unroll
    for (int i = 0; i < 8; ++i)
        #pragma unroll
        for (int j = 0; j < 4; ++j)
            acc[i][j] = (f32x4){0.f, 0.f, 0.f, 0.f};
    bf16x8 Af0[4][2], Af1[4][2], Bf[4][2];

    int colg = (tn << 8) + (wn << 6) + (lane & 15);
    float bb[4];
    #pragma unroll
    for (int n = 0; n < 4; ++n) bb[n] = bias[colg + (n << 4)];

    // ---- prologue: tile0 full + tile1 first halves; leave 6 loads in flight ----
    STGA(0, 0, 0); STGA(1, 0, 0); STGB(0, 0, 0); STGB(1, 0, 0);   // A1st(0), B1st(0)
    STGA(2, 0, 0); STGA(3, 0, 0); STGB(2, 0, 0); STGB(3, 0, 0);   // A2nd(0), B2nd(0)
    STGA(0, 1, 1); STGA(1, 1, 1); STGB(0, 1, 1); STGB(1, 1, 1);   // A1st(1), B1st(1)
    VMW(6);
    BAR;

    for (int t = 0; t < NKT; ++t) {
        int cur = t & 1, nxt = cur ^ 1;
        bool i01 = (t < NKT - 1), i23 = (t < NKT - 2);
        // phase 0: reads (mh0 frags + B nh0); stage A2nd(t+1); VMW; BAR; MFMA
        LDA(Af0, 0); LDB(0);
        if (i01) { STGA(2, t + 1, nxt); STGA(3, t + 1, nxt); VMW(6); }
        BAR;
        MM(Af0, 0, 0);
        // phase 1: reads B nh1; stage B2nd(t+1); BAR; MFMA
        LDB(1);
        if (i01) { STGB(2, t + 1, nxt); STGB(3, t + 1, nxt); }
        BAR;
        MM(Af0, 0, 1);
        // phase 2: reads mh1 frags; stage A1st(t+2) into dead cur; BAR; MFMA
        LDA(Af1, 1);
        if (i23) { STGA(0, t + 2, cur); STGA(1, t + 2, cur); }
        BAR;
        MM(Af1, 1, 0);
        // phase 3: stage B1st(t+2) into dead cur; VMW; BAR; MFMA
        if (i23)                { STGB(0, t + 2, cur); STGB(1, t + 2, cur); VMW(6); }
        else if (t == NKT - 2)  { VMW(0); }   // entering last tile: drain
        BAR;
        MM(Af1, 1, 1);
    }

    // ---- epilogue: C/D layout col=lane&15, row=(lane>>4)*4+q ----
    int rowg = (tm << 8) + (wm << 7) + ((lane >> 4) << 2);
    #pragma unroll
    for (int m = 0; m < 8; ++m) {
        #pragma unroll
        for (int n = 0; n < 4; ++n) {
            int c = colg + (n << 4);
            size_t rb = (size_t)(rowg + (m << 4)) << 11;
            #pragma unroll
            for (int q = 0; q < 4; ++q)
                out[rb + ((size_t)q << 11) + c] = acc[m][n][q] + bb[n];
        }
    }
}

extern "C" void kernel_launch(void* const* d_in, const int* in_sizes, int n_in,
                              void* d_out, int out_size, void* d_ws, size_t ws_size,
                              hipStream_t stream) {
    const float* x    = (const float*)d_in[0];   // [B,S,H] f32
    const float* W    = (const float*)d_in[1];   // [H,H] f32
    const float* bias = (const float*)d_in[2];   // [H] f32
    float* out = (float*)d_out;                  // [B,S,H] f32

    char* ws = (char*)d_ws;
    size_t s_bytes = (size_t)B_ * S_ * H_ * 2;   // 67.1 MB bf16 s
    size_t w_bytes = (size_t)H_ * H_ * 2;        // 8.4 MB bf16 W
    unsigned short* s_bf  = (unsigned short*)ws;
    short*          w_bf  = (short*)(ws + s_bytes);
    float*          carry = (float*)(ws + s_bytes + w_bytes);  // 8*8*2048 f32

    ema_cast_w<<<(H_ * H_) / 1024, 256, 0, stream>>>(W, w_bf);
    ema_carry_kernel<<<B_ * NCH * (H_ / 512), 256, 0, stream>>>(x, carry);
    ema_apply_kernel<<<B_ * NCH * (H_ / 512), 256, 0, stream>>>(x, carry, s_bf);
    ema_gemm_kernel<<<(16384 / 256) * (2048 / 256), 512, 0, stream>>>(
        (const short*)s_bf, w_bf, bias, out);
}